// Round 7
// baseline (98.830 us; speedup 1.0000x reference)
//
#include <hip/hip_runtime.h>

#define BB 8
#define CC 128
#define HH 64
#define WW 64
#define OO 128
#define KT 9
#define HWs (HH * WW)
#define BPX 32   // pixels per block

typedef __attribute__((ext_vector_type(8))) _Float16 half8;
typedef __attribute__((ext_vector_type(8))) short short8;
typedef __attribute__((ext_vector_type(8))) unsigned short ushort8;
typedef __attribute__((ext_vector_type(4))) float f32x4;

__device__ inline unsigned short f2bf(float f) {
    union { float f; unsigned int u; } x; x.f = f;
    unsigned int u = x.u;
    unsigned int r = u + 0x7fff + ((u >> 16) & 1);
    return (unsigned short)(r >> 16);
}

// ---- prep 1: NCHW f32 -> NHWC f16 (proven) ----
__global__ __launch_bounds__(256) void prep_input(
    const float* __restrict__ in, _Float16* __restrict__ out) {
    __shared__ float t[CC][33];
    int b = blockIdx.y;
    int s0 = blockIdx.x * 32;
    int s = threadIdx.x & 31;
    int c0 = threadIdx.x >> 5;
    const float* ip = in + (size_t)b * CC * HWs;
#pragma unroll
    for (int c = 0; c < CC; c += 8)
        t[c + c0][s] = ip[(size_t)(c + c0) * HWs + s0 + s];
    __syncthreads();
    int ws = threadIdx.x >> 3;
    int cg = (threadIdx.x & 7) * 16;
    _Float16 v[16];
#pragma unroll
    for (int i = 0; i < 16; ++i) v[i] = (_Float16)t[cg + i][ws];
    _Float16* op = out + ((size_t)(b * HWs) + s0 + ws) * CC + cg;
    *(half8*)op = *(half8*)&v[0];
    *(half8*)(op + 8) = *(half8*)&v[8];
}

// ---- prep 2 (proven): weight (O,C,3,3) f32 -> wbf[k][o][c] bf16 ----
__global__ __launch_bounds__(256) void prep_weight(
    const float* __restrict__ w, unsigned short* __restrict__ wbf) {
    int i = blockIdx.x * 256 + threadIdx.x;
    if (i >= KT * OO * CC) return;
    int k = i / (OO * CC);
    int r = i % (OO * CC);
    int o = r >> 7, c = r & 127;
    wbf[i] = f2bf(w[o * (CC * KT) + c * KT + k]);
}

// ---- main ----
struct GatherR {
    half8 g[4];                 // 4 corners x 8 ch
    float w00, w01, w10, w11;
};

__device__ __forceinline__ void sample_issue(
    const _Float16* __restrict__ base, int ho, int wo, int cs, int k,
    float oy, float ox, float mm, GatherR& G) {
    int kh = k / 3, kw = k % 3;
    float py = (float)(ho - 1 + kh) + oy;
    float px = (float)(wo - 1 + kw) + ox;
    float fy = floorf(py), fx = floorf(px);
    float wy1 = py - fy, wx1 = px - fx;
    float wy0 = 1.f - wy1, wx0 = 1.f - wx1;
    int y0 = (int)fy, x0 = (int)fx;
    int y1 = y0 + 1, x1 = x0 + 1;
    bool vy0 = (y0 >= 0) & (y0 < HH);
    bool vy1 = (y1 >= 0) & (y1 < HH);
    bool vx0 = (x0 >= 0) & (x0 < WW);
    bool vx1 = (x1 >= 0) & (x1 < WW);
    G.w00 = (vy0 & vx0) ? wy0 * wx0 * mm : 0.f;
    G.w01 = (vy0 & vx1) ? wy0 * wx1 * mm : 0.f;
    G.w10 = (vy1 & vx0) ? wy1 * wx0 * mm : 0.f;
    G.w11 = (vy1 & vx1) ? wy1 * wx1 * mm : 0.f;
    int y0c = min(max(y0, 0), HH - 1), y1c = min(max(y1, 0), HH - 1);
    int x0c = min(max(x0, 0), WW - 1), x1c = min(max(x1, 0), WW - 1);
    G.g[0] = *(const half8*)(base + (size_t)(y0c * WW + x0c) * CC + cs);
    G.g[1] = *(const half8*)(base + (size_t)(y0c * WW + x1c) * CC + cs);
    G.g[2] = *(const half8*)(base + (size_t)(y1c * WW + x0c) * CC + cs);
    G.g[3] = *(const half8*)(base + (size_t)(y1c * WW + x1c) * CC + cs);
}

// f32 interp (proven numerics) -> one swizzled 16-B LDS store
__device__ __forceinline__ void interp_write(
    char* lbuf, int spx, int scs, const GatherR& G) {
    ushort8 o0;
#pragma unroll
    for (int j = 0; j < 8; ++j) {
        float s = G.w00 * (float)G.g[0][j] + G.w01 * (float)G.g[1][j] +
                  G.w10 * (float)G.g[2][j] + G.w11 * (float)G.g[3][j];
        o0[j] = f2bf(s);
    }
    unsigned addr = (unsigned)(spx * 256 + ((scs * 2) ^ ((spx & 15) << 4)));
    *(ushort8*)(lbuf + addr) = o0;
}

__global__ __launch_bounds__(512, 4) void deform_main(
    const _Float16* __restrict__ inh, const unsigned short* __restrict__ wbf,
    const float* __restrict__ offset, const float* __restrict__ mask,
    const float* __restrict__ bias, float* __restrict__ out) {
    __shared__ unsigned short Al[2][BPX * CC];   // 2 x 8 KB
    __shared__ unsigned short Bl[2][OO * CC];    // 2 x 32 KB

    // 1024 blocks; XCD x owns image b=x (128 blocks each: 64 ho x 2 halves)
    int hw = blockIdx.x;
    int lb = (hw & 7) * 128 + (hw >> 3);
    int b = lb >> 7;
    int rem = lb & 127;
    int ho = rem >> 1;
    int px0 = (rem & 1) * BPX;

    int tid = threadIdx.x;
    // sampling role: 1 px x 8 ch per thread
    int spx = tid >> 4;            // 0..31
    int scs = (tid & 15) * 8;      // channel start
    int wo_s = px0 + spx;
    // B staging role: 64 B per thread (4 x 16 B)
    int o_s = tid >> 2;            // 0..127
    int cbyte = (tid & 3) * 64;    // byte col within 256-B row
    // compute role
    int wv = tid >> 6, l = tid & 63, lr = l & 15, lg = l >> 4;
    int mgrp = wv >> 2;            // px half (0..1)
    int ogrp = wv & 3;             // O quarter (0..3)

    const _Float16* base = inh + (size_t)b * HWs * CC;
    const float* offp = offset + (size_t)b * 18 * HWs + ho * WW + wo_s;
    const float* mskp = mask + (size_t)b * 9 * HWs + ho * WW + wo_s;

    f32x4 acc[2] = {};
    GatherR G;
    int4 breg[4];

    // ---- prologue ----
    {   // B(0) + gathers(0)
        const int4* src = (const int4*)((const char*)wbf + (size_t)o_s * 256 + cbyte);
#pragma unroll
        for (int j = 0; j < 4; ++j) breg[j] = src[j];
        float oy = offp[0], ox = offp[HWs], mm = mskp[0];
        sample_issue(base, ho, wo_s, scs, 0, oy, ox, mm, G);
    }
    float oyN = offp[2 * HWs], oxN = offp[3 * HWs], mmN = mskp[HWs];
    interp_write((char*)Al[0], spx, scs, G);
    {   // write B(0)
        char* dst = (char*)Bl[0] + o_s * 256;
#pragma unroll
        for (int j = 0; j < 4; ++j)
            *(int4*)(dst + ((cbyte + j * 16) ^ ((o_s & 15) << 4))) = breg[j];
    }
    {   // issue B(1) + gathers(1); prefetch offs(2)
        const int4* src = (const int4*)((const char*)wbf + (size_t)(OO * CC) * 2 +
                                        (size_t)o_s * 256 + cbyte);
#pragma unroll
        for (int j = 0; j < 4; ++j) breg[j] = src[j];
        sample_issue(base, ho, wo_s, scs, 1, oyN, oxN, mmN, G);
        oyN = offp[4 * HWs]; oxN = offp[5 * HWs]; mmN = mskp[2 * HWs];
    }
    __syncthreads();

    for (int k = 0; k < KT; ++k) {
        // (1) store tap k+1 into the other buffers (reads of them finished
        //     before the barrier that started this iteration)
        if (k < KT - 1) {
            interp_write((char*)Al[(k + 1) & 1], spx, scs, G);
            char* dst = (char*)Bl[(k + 1) & 1] + o_s * 256;
#pragma unroll
            for (int j = 0; j < 4; ++j)
                *(int4*)(dst + ((cbyte + j * 16) ^ ((o_s & 15) << 4))) = breg[j];
        }
        // (2) issue tap k+2 loads
        if (k < KT - 2) {
            const int4* src = (const int4*)((const char*)wbf +
                              (size_t)(k + 2) * OO * CC * 2 + (size_t)o_s * 256 + cbyte);
#pragma unroll
            for (int j = 0; j < 4; ++j) breg[j] = src[j];
            sample_issue(base, ho, wo_s, scs, k + 2, oyN, oxN, mmN, G);
            if (k < KT - 3) {
                oyN = offp[(2 * k + 6) * HWs];
                oxN = offp[(2 * k + 7) * HWs];
                mmN = mskp[(k + 3) * HWs];
            }
        }
        // (3) MFMA tap k from LDS[k&1]
#pragma unroll
        for (int c = 0; c < 4; ++c) {
            int arow = mgrp * 16 + lr;
            unsigned aaddr = (unsigned)(arow * 256 + ((c * 64 + lg * 16) ^ (lr << 4)));
            short8 af = *(const short8*)((const char*)Al[k & 1] + aaddr);
#pragma unroll
            for (int n = 0; n < 2; ++n) {
                int o = ogrp * 32 + n * 16 + lr;
                unsigned baddr = (unsigned)(o * 256 + ((c * 64 + lg * 16) ^ ((o & 15) << 4)));
                short8 bf = *(const short8*)((const char*)Bl[k & 1] + baddr);
                acc[n] = __builtin_amdgcn_mfma_f32_16x16x32_bf16(af, bf, acc[n], 0, 0, 0);
            }
        }
        if (k < KT - 1) __syncthreads();
    }

    // ---- epilogue ----
#pragma unroll
    for (int n = 0; n < 2; ++n) {
        int o = ogrp * 32 + n * 16 + lr;
        float bs = bias[o];
        float4 v;
        v.x = acc[n][0] + bs;
        v.y = acc[n][1] + bs;
        v.z = acc[n][2] + bs;
        v.w = acc[n][3] + bs;
        int wo0 = px0 + mgrp * 16 + lg * 4;
        *(float4*)(out + (size_t)(b * OO + o) * HWs + ho * WW + wo0) = v;
    }
}

extern "C" void kernel_launch(void* const* d_in, const int* in_sizes, int n_in,
                              void* d_out, int out_size, void* d_ws, size_t ws_size,
                              hipStream_t stream) {
    const float* inp    = (const float*)d_in[0];
    const float* offset = (const float*)d_in[1];
    const float* mask   = (const float*)d_in[2];
    const float* weight = (const float*)d_in[3];
    const float* bias   = (const float*)d_in[4];
    float* out = (float*)d_out;

    _Float16* inh = (_Float16*)d_ws;  // 8 MB
    unsigned short* wbf =
        (unsigned short*)((char*)d_ws + (size_t)BB * HWs * CC * sizeof(_Float16));

    prep_input<<<dim3(128, 8), 256, 0, stream>>>(inp, inh);
    prep_weight<<<dim3((KT * OO * CC + 255) / 256), 256, 0, stream>>>(weight, wbf);
    deform_main<<<dim3(1024), 512, 0, stream>>>(inh, wbf, offset, mask, bias, out);
}

// Round 8
// 64.754 us; speedup vs baseline: 1.5262x; 1.5262x over previous
//
#include <hip/hip_runtime.h>

#define BB 8
#define CC 128
#define HH 64
#define WW 64
#define OO 128
#define KT 9
#define HWs (HH * WW)

typedef __attribute__((ext_vector_type(8))) _Float16 half8;
typedef __attribute__((ext_vector_type(8))) short short8;
typedef __attribute__((ext_vector_type(4))) float f32x4;

__device__ inline unsigned short f2bf(float f) {
    union { float f; unsigned int u; } x; x.f = f;
    unsigned int u = x.u;
    unsigned int r = u + 0x7fff + ((u >> 16) & 1);
    return (unsigned short)(r >> 16);
}

// ---- prep 1: NCHW f32 -> NHWC f16 (proven) ----
__global__ __launch_bounds__(256) void prep_input(
    const float* __restrict__ in, _Float16* __restrict__ out) {
    __shared__ float t[CC][33];
    int b = blockIdx.y;
    int s0 = blockIdx.x * 32;
    int s = threadIdx.x & 31;
    int c0 = threadIdx.x >> 5;
    const float* ip = in + (size_t)b * CC * HWs;
#pragma unroll
    for (int c = 0; c < CC; c += 8)
        t[c + c0][s] = ip[(size_t)(c + c0) * HWs + s0 + s];
    __syncthreads();
    int ws = threadIdx.x >> 3;
    int cg = (threadIdx.x & 7) * 16;
    _Float16 v[16];
#pragma unroll
    for (int i = 0; i < 16; ++i) v[i] = (_Float16)t[cg + i][ws];
    _Float16* op = out + ((size_t)(b * HWs) + s0 + ws) * CC + cg;
    *(half8*)op = *(half8*)&v[0];
    *(half8*)(op + 8) = *(half8*)&v[8];
}

// ---- prep 2 (proven): weight (O,C,3,3) f32 -> wbf[k][o][c] bf16 ----
__global__ __launch_bounds__(256) void prep_weight(
    const float* __restrict__ w, unsigned short* __restrict__ wbf) {
    int i = blockIdx.x * 256 + threadIdx.x;
    if (i >= KT * OO * CC) return;
    int k = i / (OO * CC);
    int r = i % (OO * CC);
    int o = r >> 7, c = r & 127;
    wbf[i] = f2bf(w[o * (CC * KT) + c * KT + k]);
}

// ---- main ----
struct GatherR {
    half8 g[8];                 // [corner][cc]: 4 corners x 2 chunks of 8 ch
    float w00, w01, w10, w11;
};

__device__ __forceinline__ void sample_issue(
    const _Float16* __restrict__ base, int ho, int wo, int cs, int k,
    float oy, float ox, float mm, GatherR& G) {
    int kh = k / 3, kw = k % 3;
    float py = (float)(ho - 1 + kh) + oy;
    float px = (float)(wo - 1 + kw) + ox;
    float fy = floorf(py), fx = floorf(px);
    float wy1 = py - fy, wx1 = px - fx;
    float wy0 = 1.f - wy1, wx0 = 1.f - wx1;
    int y0 = (int)fy, x0 = (int)fx;
    int y1 = y0 + 1, x1 = x0 + 1;
    bool vy0 = (y0 >= 0) & (y0 < HH);
    bool vy1 = (y1 >= 0) & (y1 < HH);
    bool vx0 = (x0 >= 0) & (x0 < WW);
    bool vx1 = (x1 >= 0) & (x1 < WW);
    G.w00 = (vy0 & vx0) ? wy0 * wx0 * mm : 0.f;
    G.w01 = (vy0 & vx1) ? wy0 * wx1 * mm : 0.f;
    G.w10 = (vy1 & vx0) ? wy1 * wx0 * mm : 0.f;
    G.w11 = (vy1 & vx1) ? wy1 * wx1 * mm : 0.f;
    int y0c = min(max(y0, 0), HH - 1), y1c = min(max(y1, 0), HH - 1);
    int x0c = min(max(x0, 0), WW - 1), x1c = min(max(x1, 0), WW - 1);
    const _Float16* p00 = base + (size_t)(y0c * WW + x0c) * CC + cs;
    const _Float16* p01 = base + (size_t)(y0c * WW + x1c) * CC + cs;
    const _Float16* p10 = base + (size_t)(y1c * WW + x0c) * CC + cs;
    const _Float16* p11 = base + (size_t)(y1c * WW + x1c) * CC + cs;
    G.g[0] = *(const half8*)p00;  G.g[1] = *(const half8*)(p00 + 32);
    G.g[2] = *(const half8*)p01;  G.g[3] = *(const half8*)(p01 + 32);
    G.g[4] = *(const half8*)p10;  G.g[5] = *(const half8*)(p10 + 32);
    G.g[6] = *(const half8*)p11;  G.g[7] = *(const half8*)(p11 + 32);
}

__global__ __launch_bounds__(512, 4) void deform_main(
    const _Float16* __restrict__ inh, const unsigned short* __restrict__ wbf,
    const float* __restrict__ offset, const float* __restrict__ mask,
    const float* __restrict__ bias, float* __restrict__ out) {
    __shared__ unsigned short Bl[2][OO * CC];  // 2 x 32 KB

    // 512 blocks; XCD x owns batch image b = x (2 MB f16 in its 4 MB L2)
    int hw = blockIdx.x;
    int lb = (hw & 7) * 64 + (hw >> 3);
    int ho = lb & 63;
    int b = lb >> 6;

    int tid = threadIdx.x;
    int wv = tid >> 6, l = tid & 63;
    int lr = l & 15, lg = l >> 4;
    int p = wv >> 1;             // pixel quarter (0..3)
    int khalf = wv & 1;          // channel half (0..1)
    int wo = p * 16 + lr;        // this lane's pixel
    int cs = khalf * 64 + lg * 8;  // first channel chunk (second is +32)

    // B staging role: each thread 64 B of one row
    int o_s = tid >> 2;
    int cbyte = (tid & 3) * 64;

    const _Float16* base = inh + (size_t)b * HWs * CC;
    const float* offp = offset + (size_t)b * 18 * HWs + ho * WW + wo;
    const float* mskp = mask + (size_t)b * 9 * HWs + ho * WW + wo;

    f32x4 acc[8] = {};
    GatherR G;
    int4 breg[4];

    // ---- prologue ----
    {   // B(0) loads first (oldest vmem), then gathers(0)
        const int4* src = (const int4*)((const char*)wbf + (size_t)o_s * 256 + cbyte);
#pragma unroll
        for (int j = 0; j < 4; ++j) breg[j] = src[j];
        float oy = offp[0], ox = offp[HWs], mm = mskp[0];
        sample_issue(base, ho, wo, cs, 0, oy, ox, mm, G);
    }
    float oyN = offp[2 * HWs], oxN = offp[3 * HWs], mmN = mskp[HWs];
    {   // write B(0): waits only the 4 B loads (older than gathers)
        char* dst = (char*)Bl[0] + o_s * 256;
#pragma unroll
        for (int j = 0; j < 4; ++j)
            *(int4*)(dst + ((cbyte + j * 16) ^ ((o_s & 15) << 4))) = breg[j];
    }
    __syncthreads();

    for (int k = 0; k < KT; ++k) {
        // (1) interp tap k -> A fragments (regs), consumes gathers(k)
        short8 af[2];
#pragma unroll
        for (int cc = 0; cc < 2; ++cc)
#pragma unroll
            for (int j = 0; j < 8; ++j) {
                float s = G.w00 * (float)G.g[0 * 2 + cc][j] +
                          G.w01 * (float)G.g[1 * 2 + cc][j] +
                          G.w10 * (float)G.g[2 * 2 + cc][j] +
                          G.w11 * (float)G.g[3 * 2 + cc][j];
                af[cc][j] = (short)f2bf(s);
            }

        if (k < KT - 1) {
            // (2) issue B(k+1) loads (before gathers: stays older in vmcnt)
            const int4* src = (const int4*)((const char*)wbf +
                              (size_t)(k + 1) * OO * CC * 2 + (size_t)o_s * 256 + cbyte);
#pragma unroll
            for (int j = 0; j < 4; ++j) breg[j] = src[j];
            // (3) issue gathers(k+1)
            sample_issue(base, ho, wo, cs, k + 1, oyN, oxN, mmN, G);
            // (4) prefetch offsets(k+2)
            if (k < KT - 2) {
                oyN = offp[(2 * k + 4) * HWs];
                oxN = offp[(2 * k + 5) * HWs];
                mmN = mskp[(k + 2) * HWs];
            }
        }

        // (5) MFMA tap k: A regs, B from Bl[k&1] (r6-proven swizzle)
#pragma unroll
        for (int cc = 0; cc < 2; ++cc) {
            unsigned colb = (unsigned)((khalf * 2 + cc) * 64 + lg * 16);
#pragma unroll
            for (int n = 0; n < 8; ++n) {
                int o = n * 16 + lr;
                unsigned baddr = (unsigned)(o * 256 + (colb ^ (lr << 4)));
                short8 bf = *(const short8*)((const char*)Bl[k & 1] + baddr);
                acc[n] = __builtin_amdgcn_mfma_f32_16x16x32_bf16(
                    af[cc], bf, acc[n], 0, 0, 0);
            }
        }

        // (6) write B(k+1); single barrier per tap
        if (k < KT - 1) {
            char* dst = (char*)Bl[(k + 1) & 1] + o_s * 256;
#pragma unroll
            for (int j = 0; j < 4; ++j)
                *(int4*)(dst + ((cbyte + j * 16) ^ ((o_s & 15) << 4))) = breg[j];
            __syncthreads();
        }
    }

    // ---- K-split pair reduction via Bl[1] (last tap k=8 read Bl[0]) ----
    float* L = (float*)&Bl[1][0];  // 4 pairs x 16 px x 128 o = 32 KB
    if (khalf) {
#pragma unroll
        for (int n = 0; n < 8; ++n)
#pragma unroll
            for (int j = 0; j < 4; ++j)
                L[(size_t)(p * 16 + lg * 4 + j) * 128 + n * 16 + lr] = acc[n][j];
    }
    __syncthreads();
    if (!khalf) {
#pragma unroll
        for (int n = 0; n < 8; ++n) {
            int o = n * 16 + lr;
            float bs = bias[o];
            float4 v;
            v.x = acc[n][0] + bs + L[(size_t)(p * 16 + lg * 4 + 0) * 128 + o];
            v.y = acc[n][1] + bs + L[(size_t)(p * 16 + lg * 4 + 1) * 128 + o];
            v.z = acc[n][2] + bs + L[(size_t)(p * 16 + lg * 4 + 2) * 128 + o];
            v.w = acc[n][3] + bs + L[(size_t)(p * 16 + lg * 4 + 3) * 128 + o];
            int wo0 = p * 16 + lg * 4;
            *(float4*)(out + (size_t)(b * OO + o) * HWs + ho * WW + wo0) = v;
        }
    }
}

extern "C" void kernel_launch(void* const* d_in, const int* in_sizes, int n_in,
                              void* d_out, int out_size, void* d_ws, size_t ws_size,
                              hipStream_t stream) {
    const float* inp    = (const float*)d_in[0];
    const float* offset = (const float*)d_in[1];
    const float* mask   = (const float*)d_in[2];
    const float* weight = (const float*)d_in[3];
    const float* bias   = (const float*)d_in[4];
    float* out = (float*)d_out;

    _Float16* inh = (_Float16*)d_ws;  // 8 MB
    unsigned short* wbf =
        (unsigned short*)((char*)d_ws + (size_t)BB * HWs * CC * sizeof(_Float16));

    prep_input<<<dim3(128, 8), 256, 0, stream>>>(inp, inh);
    prep_weight<<<dim3((KT * OO * CC + 255) / 256), 256, 0, stream>>>(weight, wbf);
    deform_main<<<dim3(512), 512, 0, stream>>>(inh, wbf, offset, mask, bias, out);
}